// Round 11
// baseline (156.702 us; speedup 1.0000x reference)
//
#include <hip/hip_runtime.h>

// Net: x[B,2] -> fc1(2->9)+ELU -> 19 x (9->9)+ELU -> fc21(9->2) -> log_softmax
// B = 2097152. Round 11: ROLLED mid-layer loop (I-fetch theory).
// R10 postmortem: VALU-busy time == source-level issue floor; ~25% idle.
// The unrolled 21x8 body is ~12KB; each resident wave fetches its own PC
// stream -> suspected I-fetch starvation. This round rolls the 19 identical
// mid layers into a tiny (~700B) loop with 1-layer-ahead A prefetch.
// Math is bit-identical to R10.
//
// MFMA 16x16x32 f16 layouts:
//   C/D: lane L holds rows (L>>4)*4+reg        of col (L&15)   [4 f32]
//   B:   lane L holds k  = (L>>4)*8+j (j=0..7) of col (L&15)   [8 f16]
// u[0]=j0,1 relu(d0,d1); u[1]=j2,3 [relu(d2), 1.0h]; u[2]=j4,5 e(d0),e(d1);
// u[3]=j6,7 [e(d2), 1.0h-dead]. Bias col 27 (g3 j3); e2m cols k=8g+4..6.
// Neurons at rows {0,1,2,4,5,6,8,9,10} (p(i)=i+i/3) -> D reg 3 always +0.0
// -> 3 exps/lane/layer; rows 12..15 zero.
//
// ELU identity: ELU(z) = relu(z) + exp2(min(L*z,0)) - 1 (L=log2e); scales and
// the -1 folded into next layer's weights/bias in build_frags.

typedef _Float16 half8 __attribute__((ext_vector_type(8)));
typedef _Float16 h2 __attribute__((ext_vector_type(2)));
typedef float float4v __attribute__((ext_vector_type(4)));
typedef unsigned int uint4v __attribute__((ext_vector_type(4)));

extern "C" __device__ _Float16 __ocml_exp2_f16(_Float16);

constexpr int H   = 9;
constexpr int NL  = 21;    // fc1 + 19 mid + fc21
constexpr int TPW = 16;    // batch tiles (of 16 rows) per wave, 2 passes of 8
constexpr int BLK = 64;    // single-wave workgroups

__global__ void build_frags(const float* __restrict__ W1, const float* __restrict__ b1,
                            const float* __restrict__ Wmid, const float* __restrict__ bmid,
                            const float* __restrict__ W21, const float* __restrict__ b21,
                            _Float16* __restrict__ ws) {
    const float L   = 1.4426950408889634f;   // log2(e)
    const float LN2 = 0.6931471805599453f;
    int l    = blockIdx.x;      // 0..20
    int lane = threadIdx.x;     // 0..63
    int row  = lane & 15;       // A row
    int g    = lane >> 4;       // k group
    bool orow = ((row & 3) != 3) && (row < 12);   // rows {0,1,2,4,5,6,8,9,10}
    int  o    = row - (row >> 2);                 // neuron index at this row
    for (int j = 0; j < 8; ++j) {
        int k = g * 8 + j;
        float v = 0.0f;
        if (l == 0) {
            if (orow && k < 2)        v = L * W1[o * 2 + k];
            else if (orow && k == 27) v = L * b1[o];
        } else if (l <= 19) {
            const float* W = Wmid + (l - 1) * 81;
            const float* b = bmid + (l - 1) * 9;
            if (orow) {
                if (j < 3 && g < 3) {                    // relu slot
                    int r_in = g * 4 + j;
                    int i = r_in - (r_in >> 2);
                    v = W[o * 9 + i];
                } else if (j >= 4 && j < 7 && g < 3) {   // e2m slot
                    int r_in = g * 4 + (j - 4);
                    int i = r_in - (r_in >> 2);
                    v = L * W[o * 9 + i];
                } else if (k == 27) {                    // bias slot (g3 j3)
                    float s = 0.0f;
                    for (int i = 0; i < H; ++i) s += W[o * 9 + i];
                    v = L * (b[o] - s);
                }
            }
        } else {  // l == 20: logits at rows 0,1
            if (row < 2) {
                if (j < 3 && g < 3) {
                    int r_in = g * 4 + j;
                    int i = r_in - (r_in >> 2);
                    v = LN2 * W21[row * 9 + i];
                } else if (j >= 4 && j < 7 && g < 3) {
                    int r_in = g * 4 + (j - 4);
                    int i = r_in - (r_in >> 2);
                    v = W21[row * 9 + i];
                } else if (k == 27) {
                    float s = 0.0f;
                    for (int i = 0; i < H; ++i) s += W21[row * 9 + i];
                    v = b21[row] - s;
                }
            }
        }
        ws[l * 512 + lane * 8 + j] = (_Float16)v;
    }
}

// d (4 f32, d[3]==+0) -> next-layer B fragment.
// 2 pkrtz + 2 pk_max + 2 pk_min + 3 v_exp_f16 + 1 or = 10 issue slots.
__device__ __forceinline__ half8 act_to_b(float4v d) {
    const h2 Z = {(_Float16)0.f, (_Float16)0.f};
    h2 p01 = __builtin_bit_cast(h2, __builtin_amdgcn_cvt_pkrtz(d[0], d[1]));
    h2 p2b = __builtin_bit_cast(h2, __builtin_amdgcn_cvt_pkrtz(d[2], 1.0f));
    h2 r01 = __builtin_elementwise_max(p01, Z);
    h2 r2b = __builtin_elementwise_max(p2b, Z);   // [relu(d2), 1.0h bias]
    h2 t01 = __builtin_elementwise_min(p01, Z);
    h2 t2b = __builtin_elementwise_min(p2b, Z);   // [min(d2,0), 0]
    h2 e01 = __builtin_elementwise_exp2(t01);     // 2x v_exp_f16
    _Float16 e2 = __ocml_exp2_f16(t2b[0]);        // 1x v_exp_f16
    uint4v u;
    u[0] = __builtin_bit_cast(unsigned, r01);
    u[1] = __builtin_bit_cast(unsigned, r2b);
    u[2] = __builtin_bit_cast(unsigned, e01);
    u[3] = 0x3C000000u |                          // finite dead j7
           (unsigned)__builtin_bit_cast(unsigned short, e2);
    return __builtin_bit_cast(half8, u);
}

__device__ __forceinline__ float bperm(int byte_idx, float v) {
    return __builtin_bit_cast(float,
        __builtin_amdgcn_ds_bpermute(byte_idx, __builtin_bit_cast(int, v)));
}

// Wave-batched log-softmax + store for 4 tiles (dd[0..3] -> tiles gbase..+3).
__device__ __forceinline__ void softmax4(const float4v* dd, int gbase,
                                         int lane, int grp,
                                         float* __restrict__ out) {
    const float NLOG2E = -1.4426950408889634f;
    const float LN2f   = 0.6931471805599453f;
    const int bidx = (lane & 15) << 2;
    float a0 = bperm(bidx, dd[0][0]), a1 = bperm(bidx, dd[0][1]);
    float b0 = bperm(bidx, dd[1][0]), b1 = bperm(bidx, dd[1][1]);
    float c0 = bperm(bidx, dd[2][0]), c1 = bperm(bidx, dd[2][1]);
    float d0 = bperm(bidx, dd[3][0]), d1 = bperm(bidx, dd[3][1]);
    float l0 = (grp == 0) ? a0 : (grp == 1) ? b0 : (grp == 2) ? c0 : d0;
    float l1 = (grp == 0) ? a1 : (grp == 1) ? b1 : (grp == 2) ? c1 : d1;
    float mx  = fmaxf(l0, l1);
    float ad  = fabsf(l0 - l1);
    float e   = __builtin_amdgcn_exp2f(NLOG2E * ad);
    float lg  = __builtin_amdgcn_logf(1.0f + e);     // log2(1+e)
    float lse = fmaf(LN2f, lg, mx);
    ((float2*)out)[(gbase << 4) + lane] = make_float2(l0 - lse, l1 - lse);
}

__global__ __launch_bounds__(BLK, 4) void mlp_mfma(const float* __restrict__ x,
                                                   const _Float16* __restrict__ ws,
                                                   float* __restrict__ out) {
    const int lane  = threadIdx.x;        // single wave per block
    const int grp   = lane >> 4;
    const int col   = lane & 15;
    const int tile0 = blockIdx.x * TPW;   // < 131072, 32-bit safe

    const half8* wsv = (const half8*)ws;
    const unsigned g0_sel  = (grp == 0) ? 0xFFFFFFFFu : 0u;
    const unsigned bias_u1 = (grp == 3) ? 0x3C000000u : 0u;  // 1.0h @ j3 (k=27)
    const float4v ZV = {0.f, 0.f, 0.f, 0.f};

    // Load + pre-pack ALL 16 x fragments at wave start (1 VGPR each).
    unsigned xb[TPW];
    #pragma unroll
    for (int k = 0; k < TPW; ++k) {
        float2 xv = ((const float2*)x)[((tile0 + k) << 4) + col];
        xb[k] = __builtin_bit_cast(unsigned,
                    __builtin_amdgcn_cvt_pkrtz(xv.x, xv.y)) & g0_sel;
    }

    // First/last A fragments held across both passes; mids streamed in-loop.
    const half8 A0  = wsv[lane];                 // layer 0
    const half8 A20 = wsv[20 * 64 + lane];       // layer 20

    #pragma unroll
    for (int half = 0; half < 2; ++half) {
        half8 bf[8];
        #pragma unroll
        for (int k = 0; k < 8; ++k) {
            uint4v u;
            u[0] = xb[half * 8 + k];
            u[1] = bias_u1;
            u[2] = 0u; u[3] = 0u;
            bf[k] = __builtin_bit_cast(half8, u);
        }

        float4v dd[8];

        // Layer 0 + activation.
        #pragma unroll
        for (int k = 0; k < 8; ++k)
            dd[k] = __builtin_amdgcn_mfma_f32_16x16x32_f16(A0, bf[k], ZV, 0, 0, 0);
        #pragma unroll
        for (int k = 0; k < 8; ++k) bf[k] = act_to_b(dd[k]);

        // Rolled mid layers 1..19, one-layer-ahead A prefetch (~95-inst body).
        half8 Ac = wsv[64 + lane];
        #pragma unroll 1
        for (int l = 1; l <= 19; ++l) {
            half8 An = wsv[(l + 1) * 64 + lane];   // prefetch next (A20 on l=19, dead)
            #pragma unroll
            for (int k = 0; k < 8; ++k)
                dd[k] = __builtin_amdgcn_mfma_f32_16x16x32_f16(Ac, bf[k], ZV, 0, 0, 0);
            #pragma unroll
            for (int k = 0; k < 8; ++k) bf[k] = act_to_b(dd[k]);
            Ac = An;
        }

        // Layer 20 (logits).
        #pragma unroll
        for (int k = 0; k < 8; ++k)
            dd[k] = __builtin_amdgcn_mfma_f32_16x16x32_f16(A20, bf[k], ZV, 0, 0, 0);

        const int gb = tile0 + half * 8;
        softmax4(dd,     gb,     lane, grp, out);
        softmax4(dd + 4, gb + 4, lane, grp, out);
    }
}

extern "C" void kernel_launch(void* const* d_in, const int* in_sizes, int n_in,
                              void* d_out, int out_size, void* d_ws, size_t ws_size,
                              hipStream_t stream) {
    const float* x    = (const float*)d_in[0];
    const float* W1   = (const float*)d_in[1];
    const float* b1   = (const float*)d_in[2];
    const float* Wmid = (const float*)d_in[3];
    const float* bmid = (const float*)d_in[4];
    const float* W21  = (const float*)d_in[5];
    const float* b21  = (const float*)d_in[6];
    float* out = (float*)d_out;
    _Float16* ws = (_Float16*)d_ws;   // 21*512 halves = 21.5 KB

    build_frags<<<NL, 64, 0, stream>>>(W1, b1, Wmid, bmid, W21, b21, ws);

    const int nrows = in_sizes[0] / 2;           // 2097152
    const int tiles = nrows / 16;                // 131072
    const int blocks = tiles / TPW;              // 8192 single-wave blocks
    mlp_mfma<<<blocks, BLK, 0, stream>>>(x, ws, out);
}